// Round 5
// baseline (2228.043 us; speedup 1.0000x reference)
//
#include <hip/hip_runtime.h>

#define NB 4
#define NPTS 8192
#define CIN 64
#define COUT 128
#define NS 2048
#define KNBR 64
#define CAP 1024

#define TFPS 512
#define PPT 16              // points per thread
#define NWAVE 8             // waves per block

__device__ __forceinline__ unsigned spread3(unsigned v) {
    v &= 0x3FFu;
    v = (v * 0x00010001u) & 0xFF0000FFu;
    v = (v * 0x00000101u) & 0x0F00F00Fu;
    v = (v * 0x00000011u) & 0xC30C30C3u;
    v = (v * 0x00000005u) & 0x49249249u;
    return v;
}

__device__ __forceinline__ unsigned quant6(float v) {
    float q = fminf(fmaxf((v + 5.0f) * 6.4f, 0.0f), 63.0f);
    return (unsigned)(int)q;
}

// DPP max step: invalid-source lanes keep their own value (old = v).
#define DPP_UMAX(v, ctrl)                                                     \
    {                                                                         \
        unsigned _t = (unsigned)__builtin_amdgcn_update_dpp(                  \
            (int)(v), (int)(v), (ctrl), 0xF, 0xF, false);                     \
        (v) = ((v) > _t) ? (v) : _t;                                          \
    }

// ---------------------------------------------------------------------------
// FPS v5: 512 threads (8 waves -> 2/SIMD issue contention), 16 Morton-
// contiguous pts/thread. Post-barrier: speculative per-candidate spos loads
// overlap the DPP reduce; winner coords picked via readlane (no dependent
// LDS chain). Subkey = (8191-idx)<<3 | wave  ==> lexicographic max == (max
// value, lowest index), exactly jnp.argmax. md updates bit-exact.
// ---------------------------------------------------------------------------
__global__ __launch_bounds__(TFPS) void fps_kernel(
    const float* __restrict__ pos, int* __restrict__ fps_idx,
    float* __restrict__ pos_s)
{
    __shared__ float spos[NPTS * 3];          // 96 KB
    __shared__ unsigned skey[NPTS];           // 32 KB, morton<<13 | idx
    __shared__ uint2 rk[2][NWAVE];            // per-wave (value, subkey)

    const int b    = blockIdx.x;
    const int tid  = threadIdx.x;
    const int lane = tid & 63;
    const int wv   = tid >> 6;
    const float* pb = pos + (size_t)b * NPTS * 3;

    for (int i = tid; i < NPTS * 3; i += TFPS) spos[i] = pb[i];
    __syncthreads();

    for (int i = tid; i < NPTS; i += TFPS) {
        unsigned qx = quant6(spos[i * 3 + 0]);
        unsigned qy = quant6(spos[i * 3 + 1]);
        unsigned qz = quant6(spos[i * 3 + 2]);
        unsigned m  = spread3(qx) | (spread3(qy) << 1) | (spread3(qz) << 2);
        skey[i] = (m << 13) | (unsigned)i;
    }
    __syncthreads();

    // bitonic sort on morton keys (any permutation is correct; sort quality
    // only affects skip rate)
    for (int k2 = 2; k2 <= NPTS; k2 <<= 1) {
        for (int j = k2 >> 1; j > 0; j >>= 1) {
#pragma unroll
            for (int t = 0; t < NPTS / TFPS; ++t) {
                int i = tid + t * TFPS, ixj = i ^ j;
                if (ixj > i) {
                    unsigned a = skey[i], c = skey[ixj];
                    bool up = ((i & k2) == 0);
                    if ((a > c) == up) { skey[i] = c; skey[ixj] = a; }
                }
            }
            __syncthreads();
        }
    }

    float px[PPT], py[PPT], pz[PPT], md[PPT];
    unsigned oi[PPT];   // (8191 - orig_idx) << 3 | wv   (subkey per point)
    float mnx =  __builtin_inff(), mny =  __builtin_inff(), mnz =  __builtin_inff();
    float mxx = -__builtin_inff(), mxy = -__builtin_inff(), mxz = -__builtin_inff();
#pragma unroll
    for (int j = 0; j < PPT; ++j) {
        int o = (int)(skey[tid * PPT + j] & 8191u);
        oi[j] = ((8191u - (unsigned)o) << 3) | (unsigned)wv;
        float x = spos[o * 3 + 0], y = spos[o * 3 + 1], z = spos[o * 3 + 2];
        px[j] = x; py[j] = y; pz[j] = z;
        md[j] = __builtin_inff();
        mnx = fminf(mnx, x); mxx = fmaxf(mxx, x);
        mny = fminf(mny, y); mxy = fmaxf(mxy, y);
        mnz = fminf(mnz, z); mxz = fmaxf(mxz, z);
    }

    if (tid == 0) {
        fps_idx[b * NS] = 0;
        pos_s[((size_t)b * NS) * 3 + 0] = spos[0];
        pos_s[((size_t)b * NS) * 3 + 1] = spos[1];
        pos_s[((size_t)b * NS) * 3 + 2] = spos[2];
    }

    float cx = spos[0], cy = spos[1], cz = spos[2];
    unsigned long long kb = (unsigned long long)0x7F800000u << 32; // step-1 active
    unsigned cwv = 0, cws = 0;   // cached wave (value, subkey)

    for (int s = 1; s < NS; ++s) {
        const int p = s & 1;

        // conservative lower bound d2(bbox, c); skip iff provably no md change
        float umaxf = __uint_as_float((unsigned)(kb >> 32));
        float lbx = fmaxf(fmaxf(__fsub_rn(mnx, cx), __fsub_rn(cx, mxx)), 0.0f);
        float lby = fmaxf(fmaxf(__fsub_rn(mny, cy), __fsub_rn(cy, mxy)), 0.0f);
        float lbz = fmaxf(fmaxf(__fsub_rn(mnz, cz), __fsub_rn(cz, mxz)), 0.0f);
        float lb2 = lbx * lbx + lby * lby + lbz * lbz;
        bool need = (lb2 * 0.999f < umaxf);

        if (__any(need)) {
            // two independent chains to halve the compare dependency depth
            unsigned long long kb0 = 0, kb1 = 0;
#pragma unroll
            for (int j = 0; j < PPT; j += 2) {
                float dx0 = __fsub_rn(px[j], cx);
                float dy0 = __fsub_rn(py[j], cy);
                float dz0 = __fsub_rn(pz[j], cz);
                float d0  = __fadd_rn(__fadd_rn(__fmul_rn(dx0, dx0), __fmul_rn(dy0, dy0)),
                                      __fmul_rn(dz0, dz0));
                float m0  = fminf(md[j], d0);
                md[j] = m0;
                unsigned long long k0 =
                    ((unsigned long long)__float_as_uint(m0) << 32) | oi[j];
                if (k0 > kb0) kb0 = k0;

                float dx1 = __fsub_rn(px[j + 1], cx);
                float dy1 = __fsub_rn(py[j + 1], cy);
                float dz1 = __fsub_rn(pz[j + 1], cz);
                float d1  = __fadd_rn(__fadd_rn(__fmul_rn(dx1, dx1), __fmul_rn(dy1, dy1)),
                                      __fmul_rn(dz1, dz1));
                float m1  = fminf(md[j + 1], d1);
                md[j + 1] = m1;
                unsigned long long k1 =
                    ((unsigned long long)__float_as_uint(m1) << 32) | oi[j + 1];
                if (k1 > kb1) kb1 = k1;
            }
            kb = (kb1 > kb0) ? kb1 : kb0;

            // stage 1: wave argmax via DPP. Pass 1: value.
            unsigned vb = (unsigned)(kb >> 32), sb = (unsigned)kb;
            unsigned v = vb;
            DPP_UMAX(v, 0x111); DPP_UMAX(v, 0x112); DPP_UMAX(v, 0x114);
            DPP_UMAX(v, 0x118); DPP_UMAX(v, 0x142); DPP_UMAX(v, 0x143);
            unsigned vwav = (unsigned)__builtin_amdgcn_readlane((int)v, 63);
            // Pass 2: subkey among value-maximal lanes.
            unsigned sc = (vb == vwav) ? sb : 0u;
            DPP_UMAX(sc, 0x111); DPP_UMAX(sc, 0x112); DPP_UMAX(sc, 0x114);
            DPP_UMAX(sc, 0x118); DPP_UMAX(sc, 0x142); DPP_UMAX(sc, 0x143);
            unsigned swav = (unsigned)__builtin_amdgcn_readlane((int)sc, 63);
            cwv = vwav; cws = swav;
            if (lane == 0) rk[p][wv] = make_uint2(vwav, swav);
        } else {
            if (lane == 0) rk[p][wv] = make_uint2(cwv, cws);
        }
        __syncthreads();   // single barrier per step (parity double-buffer)

        // stage 2: lane l owns candidate (l&7); speculative spos loads for
        // all 8 candidates overlap the DPP reduce.
        uint2 r = rk[p][lane & (NWAVE - 1)];
        int fi_l = 8191 - (int)(r.y >> 3);
        float sx = spos[fi_l * 3 + 0];
        float sy = spos[fi_l * 3 + 1];
        float sz = spos[fi_l * 3 + 2];

        unsigned v2 = r.x;
        DPP_UMAX(v2, 0x111); DPP_UMAX(v2, 0x112); DPP_UMAX(v2, 0x114);
        unsigned vg = (unsigned)__builtin_amdgcn_readlane((int)v2, 15);
        unsigned s2 = (r.x == vg) ? r.y : 0u;
        DPP_UMAX(s2, 0x111); DPP_UMAX(s2, 0x112); DPP_UMAX(s2, 0x114);
        unsigned sg = (unsigned)__builtin_amdgcn_readlane((int)s2, 15);

        int w  = (int)(sg & 7u);           // winning wave (SGPR)
        int fi = 8191 - (int)(sg >> 3);
        cx = __uint_as_float((unsigned)__builtin_amdgcn_readlane(__float_as_int(sx), w));
        cy = __uint_as_float((unsigned)__builtin_amdgcn_readlane(__float_as_int(sy), w));
        cz = __uint_as_float((unsigned)__builtin_amdgcn_readlane(__float_as_int(sz), w));

        if (tid == 0) {
            fps_idx[b * NS + s] = fi;
            pos_s[((size_t)b * NS + s) * 3 + 0] = cx;
            pos_s[((size_t)b * NS + s) * 3 + 1] = cy;
            pos_s[((size_t)b * NS + s) * 3 + 2] = cz;
        }
    }
}

// ---------------------------------------------------------------------------
// Radius neighbors (unchanged): one block per sampled point.
// ---------------------------------------------------------------------------
__global__ __launch_bounds__(256) void radius_kernel(
    const float* __restrict__ pos, const int* __restrict__ fps_idx,
    int* __restrict__ nbr, int* __restrict__ ncnt)
{
    __shared__ unsigned long long keys[CAP];
    __shared__ int cnt;

    const int row = blockIdx.x;
    const int b   = row >> 11;
    const int tid = threadIdx.x;
    const float* pb = pos + (size_t)b * NPTS * 3;

    if (tid == 0) cnt = 0;
    __syncthreads();

    const int   ci = fps_idx[row];
    const float cx = pb[ci * 3 + 0];
    const float cy = pb[ci * 3 + 1];
    const float cz = pb[ci * 3 + 2];
    const float R2 = (float)(0.4 * 0.4);

    for (int i = tid; i < NPTS; i += 256) {
        float dx = __fsub_rn(pb[i * 3 + 0], cx);
        float dy = __fsub_rn(pb[i * 3 + 1], cy);
        float dz = __fsub_rn(pb[i * 3 + 2], cz);
        float d2 = __fadd_rn(__fadd_rn(__fmul_rn(dx, dx), __fmul_rn(dy, dy)),
                             __fmul_rn(dz, dz));
        if (d2 <= R2) {
            int p = atomicAdd(&cnt, 1);
            if (p < CAP)
                keys[p] = ((unsigned long long)__float_as_uint(d2) << 32) |
                          (unsigned)i;
        }
    }
    __syncthreads();

    int m = min(cnt, CAP);
    if (m > KNBR) {
        for (int i = m + tid; i < CAP; i += 256) keys[i] = ~0ULL;
        __syncthreads();
        for (int k2 = 2; k2 <= CAP; k2 <<= 1) {
            for (int j = k2 >> 1; j > 0; j >>= 1) {
#pragma unroll
                for (int t = 0; t < CAP / 256; ++t) {
                    int i   = tid + t * 256;
                    int ixj = i ^ j;
                    if (ixj > i) {
                        unsigned long long a = keys[i], c2 = keys[ixj];
                        bool up = ((i & k2) == 0);
                        if ((a > c2) == up) { keys[i] = c2; keys[ixj] = a; }
                    }
                }
                __syncthreads();
            }
        }
    }

    const int k = min(m, KNBR);
    if (tid == 0) ncnt[row] = k;
    for (int j = tid; j < k; j += 256)
        nbr[(size_t)row * KNBR + j] = (int)(keys[j] & 0xffffffffu);
}

// ---------------------------------------------------------------------------
// MLP + max-pool (unchanged): one wave per sampled point.
// ---------------------------------------------------------------------------
__global__ __launch_bounds__(256) void mlp_kernel(
    const float* __restrict__ x, const float* __restrict__ pos,
    const float* __restrict__ W1, const float* __restrict__ b1,
    const float* __restrict__ W2, const float* __restrict__ b2,
    const float* __restrict__ W3, const float* __restrict__ b3,
    const int* __restrict__ nbr, const int* __restrict__ ncnt,
    const float* __restrict__ pos_s, float* __restrict__ out)
{
    const int lane = threadIdx.x & 63;
    const int row  = blockIdx.x * 4 + (threadIdx.x >> 6);
    const int b    = row >> 11;
    const int cnt  = ncnt[row];
    const int slot = (lane < cnt) ? lane : 0;
    const int idx  = nbr[(size_t)row * KNBR + slot];

    const float* xr = x + ((size_t)b * NPTS + idx) * CIN;
    float feat[67];
#pragma unroll
    for (int t = 0; t < 16; ++t) {
        float4 v = *reinterpret_cast<const float4*>(xr + t * 4);
        feat[t * 4 + 0] = v.x; feat[t * 4 + 1] = v.y;
        feat[t * 4 + 2] = v.z; feat[t * 4 + 3] = v.w;
    }
    {
        const float* pr = pos + ((size_t)b * NPTS + idx) * 3;
        feat[64] = pr[0] - pos_s[(size_t)row * 3 + 0];
        feat[65] = pr[1] - pos_s[(size_t)row * 3 + 1];
        feat[66] = pr[2] - pos_s[(size_t)row * 3 + 2];
    }

    float h1[64];
#pragma unroll
    for (int o = 0; o < 64; ++o) h1[o] = b1[o];
#pragma unroll
    for (int k = 0; k < 67; ++k) {
        float f = feat[k];
#pragma unroll
        for (int o = 0; o < 64; ++o) h1[o] = fmaf(f, W1[k * 64 + o], h1[o]);
    }
#pragma unroll
    for (int o = 0; o < 64; ++o) h1[o] = fmaxf(h1[o], 0.0f);

    float h2[64];
#pragma unroll
    for (int o = 0; o < 64; ++o) h2[o] = b2[o];
#pragma unroll
    for (int k = 0; k < 64; ++k) {
        float f = h1[k];
#pragma unroll
        for (int o = 0; o < 64; ++o) h2[o] = fmaf(f, W2[k * 64 + o], h2[o]);
    }
#pragma unroll
    for (int o = 0; o < 64; ++o) h2[o] = fmaxf(h2[o], 0.0f);

    const bool valid = (lane < cnt);
    float* orow = out + (size_t)row * COUT;

#pragma unroll
    for (int c = 0; c < 4; ++c) {
        float acc[32];
#pragma unroll
        for (int o = 0; o < 32; ++o) acc[o] = b3[c * 32 + o];
#pragma unroll
        for (int k = 0; k < 64; ++k) {
            float f = h2[k];
#pragma unroll
            for (int o = 0; o < 32; ++o)
                acc[o] = fmaf(f, W3[k * 128 + c * 32 + o], acc[o]);
        }
#pragma unroll
        for (int o = 0; o < 32; ++o) {
            float v = valid ? acc[o] : -__builtin_inff();
#pragma unroll
            for (int off = 32; off; off >>= 1)
                v = fmaxf(v, __shfl_xor(v, off, 64));
            acc[o] = v;
        }
        if (lane == 0) {
#pragma unroll
            for (int q = 0; q < 8; ++q) {
                float4 v;
                v.x = acc[q * 4 + 0]; v.y = acc[q * 4 + 1];
                v.z = acc[q * 4 + 2]; v.w = acc[q * 4 + 3];
                *reinterpret_cast<float4*>(orow + c * 32 + q * 4) = v;
            }
        }
    }
}

extern "C" void kernel_launch(void* const* d_in, const int* in_sizes, int n_in,
                              void* d_out, int out_size, void* d_ws, size_t ws_size,
                              hipStream_t stream)
{
    const float* x   = (const float*)d_in[0];
    const float* pos = (const float*)d_in[1];
    const float* W1  = (const float*)d_in[2];
    const float* b1  = (const float*)d_in[3];
    const float* W2  = (const float*)d_in[4];
    const float* b2  = (const float*)d_in[5];
    const float* W3  = (const float*)d_in[6];
    const float* b3  = (const float*)d_in[7];

    float* out   = (float*)d_out;
    float* pos_s = out + (size_t)NB * NS * COUT;

    int* fpsi = (int*)d_ws;
    int* cnts = fpsi + NB * NS;
    int* nbrs = cnts + NB * NS;

    fps_kernel<<<dim3(NB), dim3(TFPS), 0, stream>>>(pos, fpsi, pos_s);
    radius_kernel<<<dim3(NB * NS), dim3(256), 0, stream>>>(pos, fpsi, nbrs, cnts);
    mlp_kernel<<<dim3(NB * NS / 4), dim3(256), 0, stream>>>(
        x, pos, W1, b1, W2, b2, W3, b3, nbrs, cnts, pos_s, out);
}

// Round 6
// 1895.523 us; speedup vs baseline: 1.1754x; 1.1754x over previous
//
#include <hip/hip_runtime.h>

#define NB 4
#define NPTS 8192
#define CIN 64
#define COUT 128
#define NS 2048
#define KNBR 64
#define CAP 1024

#define TFPS 1024
#define PPT 8               // points per thread
#define NWAVE 16            // waves per block

__device__ __forceinline__ unsigned spread3(unsigned v) {
    v &= 0x3FFu;
    v = (v * 0x00010001u) & 0xFF0000FFu;
    v = (v * 0x00000101u) & 0x0F00F00Fu;
    v = (v * 0x00000011u) & 0xC30C30C3u;
    v = (v * 0x00000005u) & 0x49249249u;
    return v;
}

__device__ __forceinline__ unsigned quant6(float v) {
    float q = fminf(fmaxf((v + 5.0f) * 6.4f, 0.0f), 63.0f);
    return (unsigned)(int)q;
}

// DPP max step: invalid-source lanes keep their own value (old = v).
#define DPP_UMAX(v, ctrl)                                                     \
    {                                                                         \
        unsigned _t = (unsigned)__builtin_amdgcn_update_dpp(                  \
            (int)(v), (int)(v), (ctrl), 0xF, 0xF, false);                     \
        (v) = ((v) > _t) ? (v) : _t;                                          \
    }

// ---------------------------------------------------------------------------
// FPS v6: R4 config (1024 thr, 8 Morton-contiguous pts/thread, bbox skip,
// DPP wave reduce) + cross-wave publication via ONE LDS u64 atomicMax per
// wave into a rotating step slot. u64 key (md_bits<<32 | 8191-idx): max ==
// (max value, lowest index) == jnp.argmax semantics exactly. Stage 2 is a
// single ds_read_b64 + decode. 4-slot rotation: tid0 zeroes slot (s+2)&3
// pre-barrier (separated from last readers and next writers by >=1 barrier).
// md updates bit-exact (plain sub/mul/add, (dx2+dy2)+dz2 order).
// ---------------------------------------------------------------------------
__global__ __launch_bounds__(TFPS) void fps_kernel(
    const float* __restrict__ pos, int* __restrict__ fps_idx,
    float* __restrict__ pos_s)
{
    __shared__ float spos[NPTS * 3];            // 96 KB
    __shared__ unsigned skey[NPTS];             // 32 KB, morton<<13 | idx
    __shared__ unsigned long long gslot[4];     // rotating step slots

    const int b    = blockIdx.x;
    const int tid  = threadIdx.x;
    const int lane = tid & 63;
    const float* pb = pos + (size_t)b * NPTS * 3;

    for (int i = tid; i < NPTS * 3; i += TFPS) spos[i] = pb[i];
    __syncthreads();

    for (int i = tid; i < NPTS; i += TFPS) {
        unsigned qx = quant6(spos[i * 3 + 0]);
        unsigned qy = quant6(spos[i * 3 + 1]);
        unsigned qz = quant6(spos[i * 3 + 2]);
        unsigned m  = spread3(qx) | (spread3(qy) << 1) | (spread3(qz) << 2);
        skey[i] = (m << 13) | (unsigned)i;
    }
    __syncthreads();

    // bitonic sort on morton keys (any permutation is correct; sort quality
    // only affects skip rate)
    for (int k2 = 2; k2 <= NPTS; k2 <<= 1) {
        for (int j = k2 >> 1; j > 0; j >>= 1) {
#pragma unroll
            for (int t = 0; t < NPTS / TFPS; ++t) {
                int i = tid + t * TFPS, ixj = i ^ j;
                if (ixj > i) {
                    unsigned a = skey[i], c = skey[ixj];
                    bool up = ((i & k2) == 0);
                    if ((a > c) == up) { skey[i] = c; skey[ixj] = a; }
                }
            }
            __syncthreads();
        }
    }

    float px[PPT], py[PPT], pz[PPT], md[PPT];
    unsigned oi[PPT];   // 8191 - orig_idx (bigger == lower original index)
    float mnx =  __builtin_inff(), mny =  __builtin_inff(), mnz =  __builtin_inff();
    float mxx = -__builtin_inff(), mxy = -__builtin_inff(), mxz = -__builtin_inff();
#pragma unroll
    for (int j = 0; j < PPT; ++j) {
        int o = (int)(skey[tid * PPT + j] & 8191u);
        oi[j] = 8191u - (unsigned)o;
        float x = spos[o * 3 + 0], y = spos[o * 3 + 1], z = spos[o * 3 + 2];
        px[j] = x; py[j] = y; pz[j] = z;
        md[j] = __builtin_inff();
        mnx = fminf(mnx, x); mxx = fmaxf(mxx, x);
        mny = fminf(mny, y); mxy = fmaxf(mxy, y);
        mnz = fminf(mnz, z); mxz = fmaxf(mxz, z);
    }

    if (tid < 4) gslot[tid] = 0ULL;
    if (tid == 0) {
        fps_idx[b * NS] = 0;
        pos_s[((size_t)b * NS) * 3 + 0] = spos[0];
        pos_s[((size_t)b * NS) * 3 + 1] = spos[1];
        pos_s[((size_t)b * NS) * 3 + 2] = spos[2];
    }
    __syncthreads();   // gslot init visible before first atomics

    float cx = spos[0], cy = spos[1], cz = spos[2];
    unsigned long long kb = (unsigned long long)0x7F800000u << 32; // step-1 active
    unsigned long long ckey = 0;   // cached wave key (valid after step 1)

    for (int s = 1; s < NS; ++s) {
        // conservative lower bound d2(bbox, c); skip iff provably no md change
        float umaxf = __uint_as_float((unsigned)(kb >> 32));
        float lbx = fmaxf(fmaxf(__fsub_rn(mnx, cx), __fsub_rn(cx, mxx)), 0.0f);
        float lby = fmaxf(fmaxf(__fsub_rn(mny, cy), __fsub_rn(cy, mxy)), 0.0f);
        float lbz = fmaxf(fmaxf(__fsub_rn(mnz, cz), __fsub_rn(cz, mxz)), 0.0f);
        float lb2 = lbx * lbx + lby * lby + lbz * lbz;
        bool need = (lb2 * 0.999f < umaxf);   // margin >> f32 rounding slop

        if (__any(need)) {
            kb = 0;
#pragma unroll
            for (int j = 0; j < PPT; ++j) {
                float dx = __fsub_rn(px[j], cx);
                float dy = __fsub_rn(py[j], cy);
                float dz = __fsub_rn(pz[j], cz);
                float d  = __fadd_rn(__fadd_rn(__fmul_rn(dx, dx), __fmul_rn(dy, dy)),
                                     __fmul_rn(dz, dz));
                float m  = fminf(md[j], d);
                md[j] = m;
                unsigned long long kj =
                    ((unsigned long long)__float_as_uint(m) << 32) | oi[j];
                if (kj > kb) kb = kj;
            }
            // wave argmax: value via DPP, subkey via ffs fast path (exact
            // DPP slow path for the rare value-tie case)
            unsigned vb = (unsigned)(kb >> 32), sb = (unsigned)kb;
            unsigned v = vb;
            DPP_UMAX(v, 0x111); DPP_UMAX(v, 0x112); DPP_UMAX(v, 0x114);
            DPP_UMAX(v, 0x118); DPP_UMAX(v, 0x142); DPP_UMAX(v, 0x143);
            unsigned vwav = (unsigned)__builtin_amdgcn_readlane((int)v, 63);
            unsigned long long tied = __ballot(vb == vwav);
            unsigned swav;
            if (tied & (tied - 1)) {          // >1 holder: exact subkey reduce
                unsigned sc = (vb == vwav) ? sb : 0u;
                DPP_UMAX(sc, 0x111); DPP_UMAX(sc, 0x112); DPP_UMAX(sc, 0x114);
                DPP_UMAX(sc, 0x118); DPP_UMAX(sc, 0x142); DPP_UMAX(sc, 0x143);
                swav = (unsigned)__builtin_amdgcn_readlane((int)sc, 63);
            } else {                          // unique holder: SALU pick
                int wl = (int)__ffsll((unsigned long long)tied) - 1;
                swav = (unsigned)__builtin_amdgcn_readlane((int)sb, wl);
            }
            ckey = ((unsigned long long)vwav << 32) | swav;
            if (lane == 0) atomicMax(&gslot[s & 3], ckey);
        } else {
            if (lane == 0) atomicMax(&gslot[s & 3], ckey);  // cached still valid
        }
        if (tid == 0) gslot[(s + 2) & 3] = 0ULL;  // safe: >=1 barrier each side
        __syncthreads();   // single barrier per step

        unsigned long long g = gslot[s & 3];
        int fi = 8191 - (int)((unsigned)g & 8191u);

        cx = spos[fi * 3 + 0];
        cy = spos[fi * 3 + 1];
        cz = spos[fi * 3 + 2];
        if (tid == 0) {
            fps_idx[b * NS + s] = fi;
            pos_s[((size_t)b * NS + s) * 3 + 0] = cx;
            pos_s[((size_t)b * NS + s) * 3 + 1] = cy;
            pos_s[((size_t)b * NS + s) * 3 + 2] = cz;
        }
    }
}

// ---------------------------------------------------------------------------
// Radius neighbors (unchanged): one block per sampled point.
// ---------------------------------------------------------------------------
__global__ __launch_bounds__(256) void radius_kernel(
    const float* __restrict__ pos, const int* __restrict__ fps_idx,
    int* __restrict__ nbr, int* __restrict__ ncnt)
{
    __shared__ unsigned long long keys[CAP];
    __shared__ int cnt;

    const int row = blockIdx.x;
    const int b   = row >> 11;
    const int tid = threadIdx.x;
    const float* pb = pos + (size_t)b * NPTS * 3;

    if (tid == 0) cnt = 0;
    __syncthreads();

    const int   ci = fps_idx[row];
    const float cx = pb[ci * 3 + 0];
    const float cy = pb[ci * 3 + 1];
    const float cz = pb[ci * 3 + 2];
    const float R2 = (float)(0.4 * 0.4);

    for (int i = tid; i < NPTS; i += 256) {
        float dx = __fsub_rn(pb[i * 3 + 0], cx);
        float dy = __fsub_rn(pb[i * 3 + 1], cy);
        float dz = __fsub_rn(pb[i * 3 + 2], cz);
        float d2 = __fadd_rn(__fadd_rn(__fmul_rn(dx, dx), __fmul_rn(dy, dy)),
                             __fmul_rn(dz, dz));
        if (d2 <= R2) {
            int p = atomicAdd(&cnt, 1);
            if (p < CAP)
                keys[p] = ((unsigned long long)__float_as_uint(d2) << 32) |
                          (unsigned)i;
        }
    }
    __syncthreads();

    int m = min(cnt, CAP);
    if (m > KNBR) {
        for (int i = m + tid; i < CAP; i += 256) keys[i] = ~0ULL;
        __syncthreads();
        for (int k2 = 2; k2 <= CAP; k2 <<= 1) {
            for (int j = k2 >> 1; j > 0; j >>= 1) {
#pragma unroll
                for (int t = 0; t < CAP / 256; ++t) {
                    int i   = tid + t * 256;
                    int ixj = i ^ j;
                    if (ixj > i) {
                        unsigned long long a = keys[i], c2 = keys[ixj];
                        bool up = ((i & k2) == 0);
                        if ((a > c2) == up) { keys[i] = c2; keys[ixj] = a; }
                    }
                }
                __syncthreads();
            }
        }
    }

    const int k = min(m, KNBR);
    if (tid == 0) ncnt[row] = k;
    for (int j = tid; j < k; j += 256)
        nbr[(size_t)row * KNBR + j] = (int)(keys[j] & 0xffffffffu);
}

// ---------------------------------------------------------------------------
// MLP + max-pool (unchanged): one wave per sampled point.
// ---------------------------------------------------------------------------
__global__ __launch_bounds__(256) void mlp_kernel(
    const float* __restrict__ x, const float* __restrict__ pos,
    const float* __restrict__ W1, const float* __restrict__ b1,
    const float* __restrict__ W2, const float* __restrict__ b2,
    const float* __restrict__ W3, const float* __restrict__ b3,
    const int* __restrict__ nbr, const int* __restrict__ ncnt,
    const float* __restrict__ pos_s, float* __restrict__ out)
{
    const int lane = threadIdx.x & 63;
    const int row  = blockIdx.x * 4 + (threadIdx.x >> 6);
    const int b    = row >> 11;
    const int cnt  = ncnt[row];
    const int slot = (lane < cnt) ? lane : 0;
    const int idx  = nbr[(size_t)row * KNBR + slot];

    const float* xr = x + ((size_t)b * NPTS + idx) * CIN;
    float feat[67];
#pragma unroll
    for (int t = 0; t < 16; ++t) {
        float4 v = *reinterpret_cast<const float4*>(xr + t * 4);
        feat[t * 4 + 0] = v.x; feat[t * 4 + 1] = v.y;
        feat[t * 4 + 2] = v.z; feat[t * 4 + 3] = v.w;
    }
    {
        const float* pr = pos + ((size_t)b * NPTS + idx) * 3;
        feat[64] = pr[0] - pos_s[(size_t)row * 3 + 0];
        feat[65] = pr[1] - pos_s[(size_t)row * 3 + 1];
        feat[66] = pr[2] - pos_s[(size_t)row * 3 + 2];
    }

    float h1[64];
#pragma unroll
    for (int o = 0; o < 64; ++o) h1[o] = b1[o];
#pragma unroll
    for (int k = 0; k < 67; ++k) {
        float f = feat[k];
#pragma unroll
        for (int o = 0; o < 64; ++o) h1[o] = fmaf(f, W1[k * 64 + o], h1[o]);
    }
#pragma unroll
    for (int o = 0; o < 64; ++o) h1[o] = fmaxf(h1[o], 0.0f);

    float h2[64];
#pragma unroll
    for (int o = 0; o < 64; ++o) h2[o] = b2[o];
#pragma unroll
    for (int k = 0; k < 64; ++k) {
        float f = h1[k];
#pragma unroll
        for (int o = 0; o < 64; ++o) h2[o] = fmaf(f, W2[k * 64 + o], h2[o]);
    }
#pragma unroll
    for (int o = 0; o < 64; ++o) h2[o] = fmaxf(h2[o], 0.0f);

    const bool valid = (lane < cnt);
    float* orow = out + (size_t)row * COUT;

#pragma unroll
    for (int c = 0; c < 4; ++c) {
        float acc[32];
#pragma unroll
        for (int o = 0; o < 32; ++o) acc[o] = b3[c * 32 + o];
#pragma unroll
        for (int k = 0; k < 64; ++k) {
            float f = h2[k];
#pragma unroll
            for (int o = 0; o < 32; ++o)
                acc[o] = fmaf(f, W3[k * 128 + c * 32 + o], acc[o]);
        }
#pragma unroll
        for (int o = 0; o < 32; ++o) {
            float v = valid ? acc[o] : -__builtin_inff();
#pragma unroll
            for (int off = 32; off; off >>= 1)
                v = fmaxf(v, __shfl_xor(v, off, 64));
            acc[o] = v;
        }
        if (lane == 0) {
#pragma unroll
            for (int q = 0; q < 8; ++q) {
                float4 v;
                v.x = acc[q * 4 + 0]; v.y = acc[q * 4 + 1];
                v.z = acc[q * 4 + 2]; v.w = acc[q * 4 + 3];
                *reinterpret_cast<float4*>(orow + c * 32 + q * 4) = v;
            }
        }
    }
}

extern "C" void kernel_launch(void* const* d_in, const int* in_sizes, int n_in,
                              void* d_out, int out_size, void* d_ws, size_t ws_size,
                              hipStream_t stream)
{
    const float* x   = (const float*)d_in[0];
    const float* pos = (const float*)d_in[1];
    const float* W1  = (const float*)d_in[2];
    const float* b1  = (const float*)d_in[3];
    const float* W2  = (const float*)d_in[4];
    const float* b2  = (const float*)d_in[5];
    const float* W3  = (const float*)d_in[6];
    const float* b3  = (const float*)d_in[7];

    float* out   = (float*)d_out;
    float* pos_s = out + (size_t)NB * NS * COUT;

    int* fpsi = (int*)d_ws;
    int* cnts = fpsi + NB * NS;
    int* nbrs = cnts + NB * NS;

    fps_kernel<<<dim3(NB), dim3(TFPS), 0, stream>>>(pos, fpsi, pos_s);
    radius_kernel<<<dim3(NB * NS), dim3(256), 0, stream>>>(pos, fpsi, nbrs, cnts);
    mlp_kernel<<<dim3(NB * NS / 4), dim3(256), 0, stream>>>(
        x, pos, W1, b1, W2, b2, W3, b3, nbrs, cnts, pos_s, out);
}